// Round 2
// baseline (492.053 us; speedup 1.0000x reference)
//
#include <hip/hip_runtime.h>

// Problem: B=8, L=2048, C=256, D=32. Four attentions (ecg/pcg intra/inter),
// out = concat(inter + scalar*intra) -> (8,2048,512) f32.
//
// Pipeline:
//   1) proj_kernel : x(f32, interleaved ecg/pcg) @ w1..w12 -> bf16 Q[4],K[4],V^T[4] in ws
//      Q pre-scaled by log2(e)/sqrt(32) so softmax uses exp2 directly.
//      V stored transposed [b][vcol][l] so flash B-fragments are contiguous.
//   2) flash_kernel (intra): out = alpha/gamma * softmax(QK^T)V   (writes all of out)
//   3) flash_kernel (inter): out += softmax(QK^T)V                (stream-ordered RMW)

typedef __bf16 v8bf __attribute__((ext_vector_type(8)));
typedef float  v4f  __attribute__((ext_vector_type(4)));

#define QSCALE 0.25500526817276613f  // log2(e)/sqrt(32)

struct ProjArgs {
  const float* x;
  const float* w[12];
  __bf16* q[4];
  __bf16* k[4];
  __bf16* vt[4];
};

// grid: (20 jobs, 256 row-tiles), block 256. Each block: 64 rows x 64 cols GEMM tile.
// jobs 0..3: paired 32-col Q/K projections; jobs 4..19: 64-col slices of the four V's.
__global__ __launch_bounds__(256) void proj_kernel(ProjArgs pa) {
  const int job = blockIdx.x;
  const int rb  = blockIdx.y * 64;
  const int tid = threadIdx.x;
  const int lane = tid & 63, wv = tid >> 6;
  const int cl = lane & 15, quad = lane >> 4;

  __shared__ __bf16 lds_a[64][136];  // 64 rows x 128 k (+8 pad; 272B row = 17*16)
  __shared__ __bf16 lds_b[64][136];  // 64 n  x 128 k (transposed weights)

  int src, dout, wc0[2], vcol0 = 0, vmode = 0;
  const float* wp[2];
  __bf16* dqk[2] = {nullptr, nullptr};
  __bf16* vdst = nullptr;
  float sc = 1.0f;
  if (job < 4) {
    dout = 32; wc0[0] = 0; wc0[1] = 0;
    switch (job) {
      case 0: src=0; wp[0]=pa.w[0]; wp[1]=pa.w[3];  dqk[0]=pa.q[0]; dqk[1]=pa.q[1]; sc=QSCALE; break;
      case 1: src=0; wp[0]=pa.w[1]; wp[1]=pa.w[10]; dqk[0]=pa.k[0]; dqk[1]=pa.k[3]; break;
      case 2: src=1; wp[0]=pa.w[6]; wp[1]=pa.w[9];  dqk[0]=pa.q[2]; dqk[1]=pa.q[3]; sc=QSCALE; break;
      default:src=1; wp[0]=pa.w[4]; wp[1]=pa.w[7];  dqk[0]=pa.k[1]; dqk[1]=pa.k[2]; break;
    }
  } else {
    const int vi = (job - 4) >> 2, t = (job - 4) & 3;
    const int widx = (vi==0) ? 2 : (vi==1) ? 11 : (vi==2) ? 5 : 8;   // w3,w12,w6,w9
    const int vbuf = (vi==0) ? 0 : (vi==1) ? 3  : (vi==2) ? 1 : 2;   // V0,V3,V1,V2
    dout = 256; vmode = 1; src = vi >> 1;                            // e,e,p,p
    wp[0] = pa.w[widx]; wp[1] = pa.w[widx];
    wc0[0] = t*64; wc0[1] = t*64 + 32;
    vcol0 = t*64; vdst = pa.vt[vbuf];
  }

  v4f acc[4];
  v4f zero4 = {0.f, 0.f, 0.f, 0.f};
#pragma unroll
  for (int i = 0; i < 4; ++i) acc[i] = zero4;

  for (int kh = 0; kh < 2; ++kh) {
    __syncthreads();
    // stage A: pick channel `src` out of interleaved x, cast to bf16
    for (int i = tid; i < 64*64; i += 256) {
      int r = i >> 6, c2 = i & 63;
      const float4 v = *(const float4*)(pa.x + ((size_t)(rb + r)*256 + kh*128 + c2*2)*2);
      lds_a[r][c2*2]   = (__bf16)(src ? v.y : v.x);
      lds_a[r][c2*2+1] = (__bf16)(src ? v.w : v.z);
    }
    // stage B transposed: lds_b[n][k] = w[k][c0+n]
    for (int h = 0; h < 2; ++h) {
      const float* w = wp[h]; const int c0 = wc0[h];
      for (int i = tid; i < 32*128; i += 256) {
        int n = i & 31, kk = i >> 5;
        lds_b[h*32 + n][kk] = (__bf16)w[(size_t)(kh*128 + kk)*dout + c0 + n];
      }
    }
    __syncthreads();
    const int mrow = wv*16 + cl;
#pragma unroll
    for (int ks = 0; ks < 4; ++ks) {
      v8bf a = *(const v8bf*)&lds_a[mrow][ks*32 + quad*8];
#pragma unroll
      for (int nt = 0; nt < 4; ++nt) {
        v8bf b = *(const v8bf*)&lds_b[nt*16 + cl][ks*32 + quad*8];
        acc[nt] = __builtin_amdgcn_mfma_f32_16x16x32_bf16(a, b, acc[nt], 0, 0, 0);
      }
    }
  }

  __syncthreads();
  if (!vmode) {
    // Q/K: row-major [16384][32] bf16
#pragma unroll
    for (int nt = 0; nt < 4; ++nt) {
      __bf16* dst = dqk[nt >> 1];
      int c = (nt & 1)*16 + cl;
#pragma unroll
      for (int r = 0; r < 4; ++r) {
        int row = rb + wv*16 + quad*4 + r;
        dst[(size_t)row*32 + c] = (__bf16)(acc[nt][r] * sc);
      }
    }
  } else {
    // V: transpose tile in LDS, write V^T[b][vcol][l] coalesced
    __bf16 (*lds_t)[72] = (__bf16 (*)[72])&lds_a[0][0];  // 144B rows (16B-aligned)
#pragma unroll
    for (int nt = 0; nt < 4; ++nt) {
      int nl = nt*16 + cl;
#pragma unroll
      for (int r = 0; r < 4; ++r)
        lds_t[nl][wv*16 + quad*4 + r] = (__bf16)acc[nt][r];
    }
    __syncthreads();
    const int bb = rb >> 11, ll0 = rb & 2047;
    // 64 rows x 64 bf16 = 512 int4 chunks (8 bf16 each); 256 threads x 2 iters
    for (int i = tid; i < 512; i += 256) {
      int nrow = i >> 3, seg = i & 7;
      *(int4*)&vdst[((size_t)(bb*256 + vcol0 + nrow))*2048 + ll0 + seg*8] =
          *(const int4*)&lds_t[nrow][seg*8];
    }
  }
}

struct FlashArgs {
  const __bf16* q[2];
  const __bf16* k[2];
  const __bf16* v[2];
  const float*  s[2];   // alpha/gamma for intra phase, unused for inter
  float* out;
  int accumulate;
};

// grid: 512 blocks, block 256 (4 waves). Each wave: 16 queries x 256 v-cols.
// flat&15 -> (z, batch) so all 32 q-tile blocks of one (attn,batch) share an XCD
// (bid%8 constant) and its 1.15MB K/V set stays L2-resident.
__global__ __launch_bounds__(256) void flash_kernel(FlashArgs fa) {
  const int flat = blockIdx.x;
  const int grp = flat & 15, qt = flat >> 4;
  const int z = grp >> 3, bb = grp & 7;
  const int l0 = qt * 64;
  const int tid = threadIdx.x;
  const int lane = tid & 63, wv = tid >> 6;
  const int cl = lane & 15, quad = lane >> 4;

  __shared__ __bf16 q_lds[64][40];      // 80B rows: 16B-aligned b128 frags
  __shared__ __bf16 k_lds[32][40];
  __shared__ __bf16 v_lds[256][40];     // V^T tile: [vcol][key]
  __shared__ __bf16 p_lds[4][16][40];   // per-wave P round-trip

  const __bf16* Q = fa.q[z];
  const __bf16* Kb = fa.k[z] + (size_t)bb*2048*32;
  const __bf16* Vb = fa.v[z] + (size_t)bb*256*2048;

  for (int i = tid; i < 512; i += 256) {
    int r = i >> 3, c4 = (i & 7)*4;
    *(int2*)&q_lds[r][c4] = *(const int2*)&Q[((size_t)(bb*2048 + l0 + r))*32 + c4];
  }
  __syncthreads();
  const v8bf qf = *(const v8bf*)&q_lds[wv*16 + cl][quad*8];

  v4f acc[16];
  v4f zero4 = {0.f, 0.f, 0.f, 0.f};
#pragma unroll
  for (int i = 0; i < 16; ++i) acc[i] = zero4;
  float m_i[4] = {-3e38f, -3e38f, -3e38f, -3e38f};
  float l_i[4] = {0.f, 0.f, 0.f, 0.f};

  for (int kt = 0; kt < 64; ++kt) {
    const int kb = kt * 32;
    __syncthreads();  // prior iteration's LDS reads complete
    {
      int r = tid >> 3, c4 = (tid & 7)*4;
      *(int2*)&k_lds[r][c4] = *(const int2*)&Kb[((size_t)(kb + r))*32 + c4];
    }
    for (int i = tid; i < 2048; i += 256) {
      int n = i >> 3, c4 = (i & 7)*4;
      *(int2*)&v_lds[n][c4] = *(const int2*)&Vb[(size_t)n*2048 + kb + c4];
    }
    __syncthreads();

    // S = Q.K^T (pre-scaled into log2 domain at proj time)
    v4f s0 = zero4, s1 = zero4;
    {
      v8bf b0 = *(const v8bf*)&k_lds[cl][quad*8];
      v8bf b1 = *(const v8bf*)&k_lds[16 + cl][quad*8];
      s0 = __builtin_amdgcn_mfma_f32_16x16x32_bf16(qf, b0, s0, 0, 0, 0);
      s1 = __builtin_amdgcn_mfma_f32_16x16x32_bf16(qf, b1, s1, 0, 0, 0);
    }

    float mt[4], p0[4], p1[4], rs[4], al[4];
#pragma unroll
    for (int r = 0; r < 4; ++r) mt[r] = fmaxf(s0[r], s1[r]);
#pragma unroll
    for (int off = 1; off < 16; off <<= 1) {
#pragma unroll
      for (int r = 0; r < 4; ++r) mt[r] = fmaxf(mt[r], __shfl_xor(mt[r], off, 64));
    }
#pragma unroll
    for (int r = 0; r < 4; ++r) {
      float mn = fmaxf(m_i[r], mt[r]);
      al[r] = exp2f(m_i[r] - mn);
      m_i[r] = mn;
      p0[r] = exp2f(s0[r] - mn);
      p1[r] = exp2f(s1[r] - mn);
      rs[r] = p0[r] + p1[r];
    }
#pragma unroll
    for (int off = 1; off < 16; off <<= 1) {
#pragma unroll
      for (int r = 0; r < 4; ++r) rs[r] += __shfl_xor(rs[r], off, 64);
    }
#pragma unroll
    for (int r = 0; r < 4; ++r) l_i[r] = l_i[r]*al[r] + rs[r];
#pragma unroll
    for (int nt = 0; nt < 16; ++nt) {
#pragma unroll
      for (int r = 0; r < 4; ++r) acc[nt][r] *= al[r];
    }
    // P: C-layout -> LDS -> A-layout (per-wave buffer, wave-internal ordering)
#pragma unroll
    for (int r = 0; r < 4; ++r) {
      p_lds[wv][quad*4 + r][cl]      = (__bf16)p0[r];
      p_lds[wv][quad*4 + r][16 + cl] = (__bf16)p1[r];
    }
    __asm__ volatile("s_waitcnt lgkmcnt(0)" ::: "memory");
    const v8bf pf = *(const v8bf*)&p_lds[wv][cl][quad*8];
#pragma unroll
    for (int nt = 0; nt < 16; ++nt) {
      v8bf vf = *(const v8bf*)&v_lds[nt*16 + cl][quad*8];
      acc[nt] = __builtin_amdgcn_mfma_f32_16x16x32_bf16(pf, vf, acc[nt], 0, 0, 0);
    }
  }

  float inv[4];
#pragma unroll
  for (int r = 0; r < 4; ++r) inv[r] = 1.0f / l_i[r];

  float* outp = fa.out + (size_t)(bb*2048)*512 + z*256;
  if (!fa.accumulate) {
    const float scv = fa.s[z][0];
#pragma unroll
    for (int nt = 0; nt < 16; ++nt) {
      int c = nt*16 + cl;
#pragma unroll
      for (int r = 0; r < 4; ++r) {
        int row = l0 + wv*16 + quad*4 + r;
        outp[(size_t)row*512 + c] = scv * acc[nt][r] * inv[r];
      }
    }
  } else {
#pragma unroll
    for (int nt = 0; nt < 16; ++nt) {
      int c = nt*16 + cl;
#pragma unroll
      for (int r = 0; r < 4; ++r) {
        int row = l0 + wv*16 + quad*4 + r;
        outp[(size_t)row*512 + c] += acc[nt][r] * inv[r];
      }
    }
  }
}

extern "C" void kernel_launch(void* const* d_in, const int* in_sizes, int n_in,
                              void* d_out, int out_size, void* d_ws, size_t ws_size,
                              hipStream_t stream) {
  (void)in_sizes; (void)n_in; (void)out_size; (void)ws_size;

  ProjArgs pa;
  pa.x = (const float*)d_in[0];
  for (int i = 0; i < 12; ++i) pa.w[i] = (const float*)d_in[1 + i];

  __bf16* wsp = (__bf16*)d_ws;
  const size_t QK = (size_t)16384 * 32;     // 524288 elems per Q/K buffer
  const size_t VT = (size_t)8 * 256 * 2048; // 4194304 elems per V^T buffer
  for (int i = 0; i < 4; ++i) pa.q[i]  = wsp + (size_t)i * QK;
  for (int i = 0; i < 4; ++i) pa.k[i]  = wsp + (size_t)(4 + i) * QK;
  for (int i = 0; i < 4; ++i) pa.vt[i] = wsp + 8*QK + (size_t)i * VT;
  // total ws use: ~42 MB bf16

  hipLaunchKernelGGL(proj_kernel, dim3(20, 256), dim3(256), 0, stream, pa);

  // intra phase: attn0 (ecg, ->cols 0..255, *alpha), attn2 (pcg, ->cols 256..511, *gamma)
  FlashArgs fi;
  fi.q[0] = pa.q[0]; fi.k[0] = pa.k[0]; fi.v[0] = pa.vt[0];
  fi.q[1] = pa.q[2]; fi.k[1] = pa.k[2]; fi.v[1] = pa.vt[2];
  fi.s[0] = (const float*)d_in[13];  // alpha
  fi.s[1] = (const float*)d_in[14];  // gamma
  fi.out = (float*)d_out; fi.accumulate = 0;
  hipLaunchKernelGGL(flash_kernel, dim3(512), dim3(256), 0, stream, fi);

  // inter phase: attn1 (ecg) += , attn3 (pcg) +=
  FlashArgs fe;
  fe.q[0] = pa.q[1]; fe.k[0] = pa.k[1]; fe.v[0] = pa.vt[1];
  fe.q[1] = pa.q[3]; fe.k[1] = pa.k[3]; fe.v[1] = pa.vt[3];
  fe.s[0] = nullptr; fe.s[1] = nullptr;
  fe.out = (float*)d_out; fe.accumulate = 1;
  hipLaunchKernelGGL(flash_kernel, dim3(512), dim3(256), 0, stream, fe);
}

// Round 3
// 391.966 us; speedup vs baseline: 1.2553x; 1.2553x over previous
//
#include <hip/hip_runtime.h>

// B=8, L=2048, C=256, D=32. Four attentions (ecg/pcg intra/inter),
// out = concat(inter + scalar*intra) -> (8,2048,512) f32.
//
// Pipeline:
//   1) deint_kernel : x f32 interleaved -> xe, xp bf16 [16384][256] (one HBM pass)
//   2) proj_kernel  : xe/xp @ w1..w12 -> bf16 Q[4] (pre-scaled log2e/sqrt(32)), K[4], V^T[4]
//   3) flash_kernel x2 (intra writes alpha/gamma * O; inter accumulates +O)
//      - 32 queries/wave, 64-key tiles, all-32x32x16 MFMA
//      - V^T tiles staged via global_load_lds (16B) into XOR-swizzled LDS, double-buffered
//      - per-wave tile-max softmax in exp2 domain; row-sum via ones-column MFMA

typedef __bf16 v8bf __attribute__((ext_vector_type(8)));
typedef float  v4f  __attribute__((ext_vector_type(4)));
typedef float  v16f __attribute__((ext_vector_type(16)));

typedef __attribute__((address_space(1))) const void gvoid;
typedef __attribute__((address_space(3))) void svoid;

#define QSCALE 0.25500526817276613f  // log2(e)/sqrt(32)

// ---------------------------------------------------------------- deinterleave
__global__ __launch_bounds__(256) void deint_kernel(const float* __restrict__ x,
                                                    __bf16* __restrict__ xe,
                                                    __bf16* __restrict__ xp) {
  const size_t i = (size_t)blockIdx.x * 256 + threadIdx.x;  // 524288 threads, 8 pairs each
  const float4* xin = (const float4*)(x + i * 16);
  float4 a = xin[0], b = xin[1], c = xin[2], d = xin[3];
  v8bf ev, pv;
  ev[0]=(__bf16)a.x; ev[1]=(__bf16)a.z; ev[2]=(__bf16)b.x; ev[3]=(__bf16)b.z;
  ev[4]=(__bf16)c.x; ev[5]=(__bf16)c.z; ev[6]=(__bf16)d.x; ev[7]=(__bf16)d.z;
  pv[0]=(__bf16)a.y; pv[1]=(__bf16)a.w; pv[2]=(__bf16)b.y; pv[3]=(__bf16)b.w;
  pv[4]=(__bf16)c.y; pv[5]=(__bf16)c.w; pv[6]=(__bf16)d.y; pv[7]=(__bf16)d.w;
  *(v8bf*)(xe + i * 8) = ev;
  *(v8bf*)(xp + i * 8) = pv;
}

// ---------------------------------------------------------------- projections
struct ProjArgs {
  const __bf16* xe;
  const __bf16* xp;
  const float* w[12];
  __bf16* q[4];
  __bf16* k[4];
  __bf16* vt[4];
};

// grid: (20 jobs, 256 row-tiles), block 256. 64 rows x 64 cols per block, K=256 one pass.
// jobs 0..3: paired 32-col Q/K projections; jobs 4..19: 64-col slices of the four V's.
__global__ __launch_bounds__(256) void proj_kernel(ProjArgs pa) {
  const int job = blockIdx.x;
  const int rb  = blockIdx.y * 64;
  const int tid = threadIdx.x;
  const int lane = tid & 63, wv = tid >> 6;
  const int cl = lane & 15, quad = lane >> 4;

  __shared__ __bf16 lds_b[64][264];  // 64 n x 256 k (+8 pad; 528B rows, 16B aligned)

  int src, dout, wc0[2], vcol0 = 0, vmode = 0;
  const float* wp[2];
  __bf16* dqk[2] = {nullptr, nullptr};
  __bf16* vdst = nullptr;
  float sc = 1.0f;
  if (job < 4) {
    dout = 32; wc0[0] = 0; wc0[1] = 0;
    switch (job) {
      case 0: src=0; wp[0]=pa.w[0]; wp[1]=pa.w[3];  dqk[0]=pa.q[0]; dqk[1]=pa.q[1]; sc=QSCALE; break;
      case 1: src=0; wp[0]=pa.w[1]; wp[1]=pa.w[10]; dqk[0]=pa.k[0]; dqk[1]=pa.k[3]; break;
      case 2: src=1; wp[0]=pa.w[6]; wp[1]=pa.w[9];  dqk[0]=pa.q[2]; dqk[1]=pa.q[3]; sc=QSCALE; break;
      default:src=1; wp[0]=pa.w[4]; wp[1]=pa.w[7];  dqk[0]=pa.k[1]; dqk[1]=pa.k[2]; break;
    }
  } else {
    const int vi = (job - 4) >> 2, t = (job - 4) & 3;
    const int widx = (vi==0) ? 2 : (vi==1) ? 11 : (vi==2) ? 5 : 8;   // w3,w12,w6,w9
    const int vbuf = (vi==0) ? 0 : (vi==1) ? 3  : (vi==2) ? 1 : 2;   // V0,V3,V1,V2
    dout = 256; vmode = 1; src = vi >> 1;                            // e,e,p,p
    wp[0] = pa.w[widx]; wp[1] = pa.w[widx];
    wc0[0] = t*64; wc0[1] = t*64 + 32;
    vcol0 = t*64; vdst = pa.vt[vbuf];
  }

  // stage B transposed: lds_b[n][k] = w[k][c0+n]
  for (int h = 0; h < 2; ++h) {
    const float* w = wp[h]; const int c0 = wc0[h];
    for (int i = tid; i < 32*256; i += 256) {
      int n = i & 31, kk = i >> 5;
      lds_b[h*32 + n][kk] = (__bf16)w[(size_t)kk*dout + c0 + n];
    }
  }
  __syncthreads();

  const __bf16* X = src ? pa.xp : pa.xe;
  const __bf16* xrow = X + (size_t)(rb + wv*16 + cl) * 256;  // A[m=cl] row, direct global

  v4f acc[4];
  v4f zero4 = {0.f, 0.f, 0.f, 0.f};
#pragma unroll
  for (int i = 0; i < 4; ++i) acc[i] = zero4;

#pragma unroll
  for (int ks = 0; ks < 8; ++ks) {
    v8bf a = *(const v8bf*)&xrow[ks*32 + quad*8];
#pragma unroll
    for (int nt = 0; nt < 4; ++nt) {
      v8bf b = *(const v8bf*)&lds_b[nt*16 + cl][ks*32 + quad*8];
      acc[nt] = __builtin_amdgcn_mfma_f32_16x16x32_bf16(a, b, acc[nt], 0, 0, 0);
    }
  }

  __syncthreads();
  if (!vmode) {
    // Q/K: row-major [16384][32] bf16
#pragma unroll
    for (int nt = 0; nt < 4; ++nt) {
      __bf16* dst = dqk[nt >> 1];
      int c = (nt & 1)*16 + cl;
#pragma unroll
      for (int r = 0; r < 4; ++r) {
        int row = rb + wv*16 + quad*4 + r;
        dst[(size_t)row*32 + c] = (__bf16)(acc[nt][r] * sc);
      }
    }
  } else {
    // V: transpose tile in LDS (reusing lds_b), write V^T[b][vcol][l] coalesced
    __bf16 (*lds_t)[72] = (__bf16 (*)[72])&lds_b[0][0];  // 144B rows
#pragma unroll
    for (int nt = 0; nt < 4; ++nt) {
      int nl = nt*16 + cl;
#pragma unroll
      for (int r = 0; r < 4; ++r)
        lds_t[nl][wv*16 + quad*4 + r] = (__bf16)acc[nt][r];
    }
    __syncthreads();
    const int bb = rb >> 11, ll0 = rb & 2047;
    // 64 rows x 64 bf16 = 512 int4 chunks (8 bf16 each)
    for (int i = tid; i < 512; i += 256) {
      int nrow = i >> 3, seg = i & 7;
      *(int4*)&vdst[((size_t)(bb*256 + vcol0 + nrow))*2048 + ll0 + seg*8] =
          *(const int4*)&lds_t[nrow][seg*8];
    }
  }
}

// ---------------------------------------------------------------- flash attention
struct FlashArgs {
  const __bf16* q[2];
  const __bf16* k[2];
  const __bf16* v[2];
  const float*  s[2];
  float* out;
  int accumulate;
};

// grid 512 blocks (flat&15 -> (z,batch): XCD-local K/V), block 128 (2 waves).
// Each wave: 32 queries x 256 v-cols; 32 iterations of 64 keys.
__global__ __launch_bounds__(128) void flash_kernel(FlashArgs fa) {
  const int flat = blockIdx.x;
  const int grp = flat & 15, qt = flat >> 4;   // qt 0..31 (64-query block tiles)
  const int z = grp >> 3, bb = grp & 7;
  const int tid = threadIdx.x;
  const int lane = tid & 63, w = tid >> 6;
  const int l31 = lane & 31, lh = lane >> 5;
  const int l7 = lane & 7, l8 = lane >> 3;

  __shared__ __bf16 v_lds[2][16384];   // 2 bufs x 256 vcols x 64 keys; rows 128B, XOR-swizzled
  __shared__ __bf16 p_lds[2][32][72];  // per-wave P round-trip, 144B rows

  const __bf16* Q  = fa.q[z];
  const __bf16* Kb = fa.k[z] + (size_t)bb*2048*32;
  const __bf16* Vb = fa.v[z] + (size_t)bb*256*2048;

  // Q A-fragments (resident): A[m=l31][k = c*16 + lh*8 + j]
  const int qrow = qt*64 + w*32 + l31;
  const v8bf qa0 = *(const v8bf*)&Q[((size_t)(bb*2048 + qrow))*32 + 0  + lh*8];
  const v8bf qa1 = *(const v8bf*)&Q[((size_t)(bb*2048 + qrow))*32 + 16 + lh*8];

  // per-lane global base for V staging: row = w*128 + i*8 + l8 ; swizzled chunk = l7^l8
  const char* vg = (const char*)Vb + (size_t)(w*128 + l8)*4096 + (size_t)(l7 ^ l8)*16;

  // per-lane swizzled LDS read offsets (elements) for the 4 key-chunks of 16
  int voff[4];
#pragma unroll
  for (int kc = 0; kc < 4; ++kc)
    voff[kc] = l31*64 + (((kc*2 + lh) ^ l7) * 8);

  v8bf ones;
#pragma unroll
  for (int i = 0; i < 8; ++i) ones[i] = (__bf16)1.0f;

  v16f acc[8], accl;
#pragma unroll
  for (int n = 0; n < 8; ++n)
#pragma unroll
    for (int i = 0; i < 16; ++i) acc[n][i] = 0.f;
#pragma unroll
  for (int i = 0; i < 16; ++i) accl[i] = 0.f;
  float m_i = -1e30f;

  // stage kt=0 into buf 0
  {
    const char* g = vg;
#pragma unroll
    for (int i = 0; i < 16; ++i)
      __builtin_amdgcn_global_load_lds((gvoid*)(g + (size_t)i*32768),
                                       (svoid*)&v_lds[0][(w*128 + i*8)*64], 16, 0, 0);
  }
  __syncthreads();

  for (int kt = 0; kt < 32; ++kt) {
    const int cur = kt & 1;
    const int kb = kt * 64;

    // K B-fragments for this iter: B[n = key = c2*32+l31][k = c*16 + lh*8 + j]
    v8bf kf[2][2];
#pragma unroll
    for (int c2 = 0; c2 < 2; ++c2)
#pragma unroll
      for (int c = 0; c < 2; ++c)
        kf[c2][c] = *(const v8bf*)&Kb[((size_t)(kb + c2*32 + l31))*32 + c*16 + lh*8];

    // stage next V tile into the other buffer (async)
    if (kt < 31) {
      const char* g = vg + (size_t)(kt + 1) * 128;
#pragma unroll
      for (int i = 0; i < 16; ++i)
        __builtin_amdgcn_global_load_lds((gvoid*)(g + (size_t)i*32768),
                                         (svoid*)&v_lds[cur ^ 1][(w*128 + i*8)*64], 16, 0, 0);
    }

    // S = Q.K^T (log2 domain), 32q x 64k as two 32x32 tiles
    v16f s0, s1;
#pragma unroll
    for (int i = 0; i < 16; ++i) { s0[i] = 0.f; s1[i] = 0.f; }
    s0 = __builtin_amdgcn_mfma_f32_32x32x16_bf16(qa0, kf[0][0], s0, 0, 0, 0);
    s0 = __builtin_amdgcn_mfma_f32_32x32x16_bf16(qa1, kf[0][1], s0, 0, 0, 0);
    s1 = __builtin_amdgcn_mfma_f32_32x32x16_bf16(qa0, kf[1][0], s1, 0, 0, 0);
    s1 = __builtin_amdgcn_mfma_f32_32x32x16_bf16(qa1, kf[1][1], s1, 0, 0, 0);

    // wave-uniform tile max (upper bound of all row maxima -> stable)
    float mt;
    {
      v16f mx;
#pragma unroll
      for (int i = 0; i < 16; ++i) mx[i] = fmaxf(s0[i], s1[i]);
      mt = mx[0];
#pragma unroll
      for (int i = 1; i < 16; ++i) mt = fmaxf(mt, mx[i]);
#pragma unroll
      for (int off = 1; off < 64; off <<= 1) mt = fmaxf(mt, __shfl_xor(mt, off, 64));
    }
    const float mnew = fmaxf(m_i, mt);
    const float al = __builtin_exp2f(m_i - mnew);
    m_i = mnew;

    // P = exp2(S - m), store to per-wave LDS in [q][key] layout
#pragma unroll
    for (int reg = 0; reg < 16; ++reg) {
      const int row = (reg & 3) + 8*(reg >> 2) + 4*lh;
      p_lds[w][row][l31]      = (__bf16)__builtin_exp2f(s0[reg] - mnew);
      p_lds[w][row][32 + l31] = (__bf16)__builtin_exp2f(s1[reg] - mnew);
    }

    // rescale accumulators (al is wave-uniform)
#pragma unroll
    for (int n = 0; n < 8; ++n)
#pragma unroll
      for (int i = 0; i < 16; ++i) acc[n][i] *= al;
#pragma unroll
    for (int i = 0; i < 16; ++i) accl[i] *= al;

    __asm__ volatile("s_waitcnt lgkmcnt(0)" ::: "memory");

    // PV += P @ V^T  (and row-sums via ones B-fragment)
    const __bf16* vb = &v_lds[cur][0];
#pragma unroll
    for (int kc = 0; kc < 4; ++kc) {
      const v8bf pf = *(const v8bf*)&p_lds[w][l31][kc*16 + lh*8];
      accl = __builtin_amdgcn_mfma_f32_32x32x16_bf16(pf, ones, accl, 0, 0, 0);
#pragma unroll
      for (int nt = 0; nt < 8; ++nt) {
        const v8bf vf = *(const v8bf*)&vb[nt*2048 + voff[kc]];
        acc[nt] = __builtin_amdgcn_mfma_f32_32x32x16_bf16(pf, vf, acc[nt], 0, 0, 0);
      }
    }
    __syncthreads();  // drains staging (vmcnt) + LDS reads before buffer reuse
  }

  // epilogue: out[row][col] (+)= (scale*) acc/l
  float* outp = fa.out + (size_t)(bb*2048 + qt*64 + w*32) * 512 + z*256;
  if (!fa.accumulate) {
    const float scv = fa.s[z][0];
#pragma unroll
    for (int reg = 0; reg < 16; ++reg) {
      const int row = (reg & 3) + 8*(reg >> 2) + 4*lh;
      const float f = scv / accl[reg];
#pragma unroll
      for (int nt = 0; nt < 8; ++nt)
        outp[(size_t)row*512 + nt*32 + l31] = acc[nt][reg] * f;
    }
  } else {
#pragma unroll
    for (int reg = 0; reg < 16; ++reg) {
      const int row = (reg & 3) + 8*(reg >> 2) + 4*lh;
      const float f = 1.0f / accl[reg];
#pragma unroll
      for (int nt = 0; nt < 8; ++nt)
        outp[(size_t)row*512 + nt*32 + l31] += acc[nt][reg] * f;
    }
  }
}

// ---------------------------------------------------------------- launch
extern "C" void kernel_launch(void* const* d_in, const int* in_sizes, int n_in,
                              void* d_out, int out_size, void* d_ws, size_t ws_size,
                              hipStream_t stream) {
  (void)in_sizes; (void)n_in; (void)out_size; (void)ws_size;

  __bf16* wsp = (__bf16*)d_ws;
  const size_t XE = (size_t)16384 * 256;    // 4,194,304 per channel
  const size_t QK = (size_t)16384 * 32;     // 524,288 per Q/K buffer
  const size_t VT = (size_t)8 * 256 * 2048; // 4,194,304 per V^T buffer

  __bf16* xe = wsp;
  __bf16* xp = wsp + XE;

  ProjArgs pa;
  pa.xe = xe; pa.xp = xp;
  const float* x = (const float*)d_in[0];
  for (int i = 0; i < 12; ++i) pa.w[i] = (const float*)d_in[1 + i];
  __bf16* base = wsp + 2*XE;
  for (int i = 0; i < 4; ++i) pa.q[i]  = base + (size_t)i * QK;
  for (int i = 0; i < 4; ++i) pa.k[i]  = base + (size_t)(4 + i) * QK;
  for (int i = 0; i < 4; ++i) pa.vt[i] = base + 8*QK + (size_t)i * VT;
  // total ws: ~56 MB

  hipLaunchKernelGGL(deint_kernel, dim3(2048), dim3(256), 0, stream, x, xe, xp);
  hipLaunchKernelGGL(proj_kernel, dim3(20, 256), dim3(256), 0, stream, pa);

  FlashArgs fi;
  fi.q[0] = pa.q[0]; fi.k[0] = pa.k[0]; fi.v[0] = pa.vt[0];
  fi.q[1] = pa.q[2]; fi.k[1] = pa.k[2]; fi.v[1] = pa.vt[2];
  fi.s[0] = (const float*)d_in[13];  // alpha
  fi.s[1] = (const float*)d_in[14];  // gamma
  fi.out = (float*)d_out; fi.accumulate = 0;
  hipLaunchKernelGGL(flash_kernel, dim3(512), dim3(128), 0, stream, fi);

  FlashArgs fe;
  fe.q[0] = pa.q[1]; fe.k[0] = pa.k[1]; fe.v[0] = pa.vt[1];
  fe.q[1] = pa.q[3]; fe.k[1] = pa.k[3]; fe.v[1] = pa.vt[3];
  fe.s[0] = nullptr; fe.s[1] = nullptr;
  fe.out = (float*)d_out; fe.accumulate = 1;
  hipLaunchKernelGGL(flash_kernel, dim3(512), dim3(128), 0, stream, fe);
}